// Round 1
// baseline (867.903 us; speedup 1.0000x reference)
//
#include <hip/hip_runtime.h>
#include <hip/hip_bf16.h>

// EGCL: B=8, N=256, NF=128, H=128
// Factorization: edge_input@ew1 = T0[b,i] + T1[b,j] + dist*ew1[256] + adj*ew1[257]
//   T0[b,i,h] = sum_f nf[b,i,f]*ew1[f,h]
//   T1[b,j,h] = sum_f nf[b,j,f]*ew1[128+f,h]
// Then per edge: h1 = silu(pre); m = silu(h1@ew2); c1 = silu(m@cw1);
//   coord = c1.cw2; gate = sigmoid(m.iw);
//   msg[b,i] += m*gate; posdelta[b,i] += vecn*coord
// Node MLP per (b,i) afterwards, all in one block.

#define BB 8
#define NN 256
#define NFD 128
#define HD 128
#define JT 16          // j-tile size
#define NTILES (NN/JT)

__device__ __forceinline__ float sigmoidf_(float x){ return 1.0f/(1.0f+__expf(-x)); }
__device__ __forceinline__ float siluf_(float x){ return x/(1.0f+__expf(-x)); }

__global__ __launch_bounds__(128) void precompute_T(
    const float* __restrict__ nf, const float* __restrict__ ew1,
    float* __restrict__ T0, float* __restrict__ T1)
{
    __shared__ float nfs[NFD];
    const int bi = blockIdx.x;     // b*N + i
    const int h  = threadIdx.x;    // 0..127
    nfs[h] = nf[bi*NFD + h];
    __syncthreads();
    float a0 = 0.f, a1 = 0.f;
    #pragma unroll 4
    for (int f = 0; f < NFD; ++f){
        const float v = nfs[f];
        a0 = fmaf(v, ew1[f*HD + h],        a0);
        a1 = fmaf(v, ew1[(NFD+f)*HD + h],  a1);
    }
    T0[bi*HD + h] = a0;
    T1[bi*HD + h] = a1;
}

__global__ __launch_bounds__(256) void egcl_main(
    const float* __restrict__ nf,  const float* __restrict__ pos,
    const float* __restrict__ valid, const float* __restrict__ adj,
    const float* __restrict__ ew1, const float* __restrict__ ew2,
    const float* __restrict__ cw1, const float* __restrict__ cw2,
    const float* __restrict__ nw1, const float* __restrict__ nw2,
    const float* __restrict__ iw,
    const float* __restrict__ T0,  const float* __restrict__ T1,
    float* __restrict__ out)
{
    __shared__ float h1t[JT][HD];   // reused as c1t in phase GEMM2
    __shared__ float h2t[JT][HD];   // m_ij (ungated)
    __shared__ float cw2l[HD], iwl[HD];
    __shared__ float gatel[JT], coordl[JT];
    __shared__ float msgp[2][HD];
    __shared__ float ni[2*HD];
    __shared__ float posr[JT][3];
    __shared__ float n1l[HD];
    __shared__ float np[2][HD];

    const int bi  = blockIdx.x;      // b*N + i
    const int b   = bi >> 8;
    const int tid = threadIdx.x;
    const int h   = tid & (HD-1);    // 0..127
    const int jg  = tid >> 7;        // 0/1

    if (tid < HD){ cw2l[tid] = cw2[tid]; iwl[tid] = iw[tid]; }

    const float T0r   = T0[bi*HD + h];
    const float w256r = ew1[256*HD + h];
    const float w257r = ew1[257*HD + h];
    const float pix = pos[bi*3+0], piy = pos[bi*3+1], piz = pos[bi*3+2];
    const float validi = valid[bi];

    const float* __restrict__ T1b    = T1  + (size_t)(b*NN)*HD;
    const float* __restrict__ adjrow = adj + (size_t)bi*NN;
    const float* __restrict__ posb   = pos + (size_t)(b*NN)*3;

    float msgacc = 0.f;
    float pax = 0.f, pay = 0.f, paz = 0.f;   // only tid<16 meaningful

    __syncthreads();

    for (int tile = 0; tile < NTILES; ++tile){
        const int j0 = tile*JT;

        // ---- phase 1: h1 = silu(first-layer preact) for 16 j's ----
        #pragma unroll
        for (int t = 0; t < 8; ++t){
            const int jj = jg*8 + t;
            const int j  = j0 + jj;
            const float pjx = posb[j*3+0], pjy = posb[j*3+1], pjz = posb[j*3+2];
            const float dx = pix-pjx, dy = piy-pjy, dz = piz-pjz;
            const float d2 = dx*dx + dy*dy + dz*dz;
            const float aj = adjrow[j];
            const float pre = T0r + T1b[(size_t)j*HD + h] + d2*w256r + aj*w257r;
            h1t[jj][h] = siluf_(pre);
        }
        __syncthreads();  // B1

        // ---- GEMM1: m = silu(h1 @ ew2) ----
        float acc[8];
        #pragma unroll
        for (int t = 0; t < 8; ++t) acc[t] = 0.f;
        for (int k = 0; k < HD; k += 4){
            const float w0 = ew2[(k+0)*HD + h];
            const float w1 = ew2[(k+1)*HD + h];
            const float w2 = ew2[(k+2)*HD + h];
            const float w3 = ew2[(k+3)*HD + h];
            #pragma unroll
            for (int t = 0; t < 8; ++t){
                const float4 hv = *reinterpret_cast<const float4*>(&h1t[jg*8+t][k]);
                acc[t] = fmaf(hv.x, w0, acc[t]);
                acc[t] = fmaf(hv.y, w1, acc[t]);
                acc[t] = fmaf(hv.z, w2, acc[t]);
                acc[t] = fmaf(hv.w, w3, acc[t]);
            }
        }
        float h2r[8];
        #pragma unroll
        for (int t = 0; t < 8; ++t) h2r[t] = siluf_(acc[t]);
        #pragma unroll
        for (int t = 0; t < 8; ++t) h2t[jg*8+t][h] = h2r[t];
        __syncthreads();  // B2 (h1t reads done, h2t ready)

        // ---- GEMM2: c1 = silu(m @ cw1), store into h1t buffer ----
        #pragma unroll
        for (int t = 0; t < 8; ++t) acc[t] = 0.f;
        for (int k = 0; k < HD; k += 4){
            const float w0 = cw1[(k+0)*HD + h];
            const float w1 = cw1[(k+1)*HD + h];
            const float w2 = cw1[(k+2)*HD + h];
            const float w3 = cw1[(k+3)*HD + h];
            #pragma unroll
            for (int t = 0; t < 8; ++t){
                const float4 hv = *reinterpret_cast<const float4*>(&h2t[jg*8+t][k]);
                acc[t] = fmaf(hv.x, w0, acc[t]);
                acc[t] = fmaf(hv.y, w1, acc[t]);
                acc[t] = fmaf(hv.z, w2, acc[t]);
                acc[t] = fmaf(hv.w, w3, acc[t]);
            }
        }
        #pragma unroll
        for (int t = 0; t < 8; ++t) h1t[jg*8+t][h] = siluf_(acc[t]);
        __syncthreads();  // B3 (c1t ready)

        // ---- reductions: gate = sigmoid(m.iw), coord = c1.cw2 ----
        {
            const int jj  = tid >> 4;   // 0..15
            const int l16 = tid & 15;
            float pg = 0.f, pc = 0.f;
            #pragma unroll
            for (int m = 0; m < 8; ++m){
                const int hh = l16 + m*16;
                pg = fmaf(h2t[jj][hh], iwl[hh],  pg);
                pc = fmaf(h1t[jj][hh], cw2l[hh], pc);
            }
            #pragma unroll
            for (int off = 8; off >= 1; off >>= 1){
                pg += __shfl_xor(pg, off, 16);
                pc += __shfl_xor(pc, off, 16);
            }
            if (l16 == 0){ gatel[jj] = sigmoidf_(pg); coordl[jj] = pc; }
        }
        __syncthreads();  // B4 (gate/coord ready)

        // ---- message accumulation ----
        #pragma unroll
        for (int t = 0; t < 8; ++t)
            msgacc = fmaf(h2r[t], gatel[jg*8+t], msgacc);

        // ---- position accumulation (threads 0..15, one j each) ----
        if (tid < JT){
            const int j = j0 + tid;
            const float pjx = posb[j*3+0], pjy = posb[j*3+1], pjz = posb[j*3+2];
            const float dx = pix-pjx, dy = piy-pjy, dz = piz-pjz;
            const float d2 = dx*dx + dy*dy + dz*dz;
            const float nrm = sqrtf(d2);
            const float inv = 1.0f / fmaxf(nrm, 1e-10f);
            const float cd  = coordl[tid] * inv;
            pax = fmaf(dx, cd, pax);
            pay = fmaf(dy, cd, pay);
            paz = fmaf(dz, cd, paz);
        }
        __syncthreads();  // B5 (safety: gate/coord reads done before next tile)
    }

    // ---- finalize message + pos_new ----
    msgp[jg][h] = msgacc;
    if (tid < JT){ posr[tid][0]=pax; posr[tid][1]=pay; posr[tid][2]=paz; }
    __syncthreads();

    const float scale = validi * (1.0f/NN);
    if (tid < HD){
        const float m = (msgp[0][tid] + msgp[1][tid]) * scale;
        ni[tid]      = nf[(size_t)bi*NFD + tid];
        ni[HD + tid] = m;
    }
    if (tid < 3){
        float s = 0.f;
        #pragma unroll
        for (int r = 0; r < JT; ++r) s += posr[r][tid];
        const float base = (tid==0) ? pix : ((tid==1) ? piy : piz);
        out[(size_t)bi*3 + tid] = base + s*scale;
    }
    __syncthreads();

    // ---- node MLP layer 1: n1 = silu(ni @ nw1), split K over jg ----
    float p1 = 0.f;
    for (int f = 0; f < HD; ++f){
        const int ff = jg*HD + f;
        p1 = fmaf(ni[ff], nw1[ff*HD + h], p1);
    }
    np[jg][h] = p1;
    __syncthreads();
    if (tid < HD) n1l[tid] = siluf_(np[0][tid] + np[1][tid]);
    __syncthreads();

    // ---- node MLP layer 2 + residual ----
    float p2 = 0.f;
    for (int k = 0; k < 64; ++k){
        const int kk = jg*64 + k;
        p2 = fmaf(n1l[kk], nw2[kk*HD + h], p2);
    }
    np[jg][h] = p2;
    __syncthreads();
    if (tid < HD){
        out[(size_t)BB*NN*3 + (size_t)bi*HD + tid] =
            nf[(size_t)bi*NFD + tid] + np[0][tid] + np[1][tid];
    }
}

extern "C" void kernel_launch(void* const* d_in, const int* in_sizes, int n_in,
                              void* d_out, int out_size, void* d_ws, size_t ws_size,
                              hipStream_t stream)
{
    const float* nf    = (const float*)d_in[0];
    const float* pos   = (const float*)d_in[1];
    const float* valid = (const float*)d_in[2];
    const float* adj   = (const float*)d_in[3];
    const float* ew1   = (const float*)d_in[4];
    const float* ew2   = (const float*)d_in[5];
    const float* cw1   = (const float*)d_in[6];
    const float* cw2   = (const float*)d_in[7];
    const float* nw1   = (const float*)d_in[8];
    const float* nw2   = (const float*)d_in[9];
    const float* iw    = (const float*)d_in[10];
    float* out = (float*)d_out;

    float* T0 = (float*)d_ws;                 // B*N*H floats = 1 MB
    float* T1 = T0 + (size_t)BB*NN*HD;        // 1 MB

    hipLaunchKernelGGL(precompute_T, dim3(BB*NN), dim3(NFD), 0, stream,
                       nf, ew1, T0, T1);
    hipLaunchKernelGGL(egcl_main, dim3(BB*NN), dim3(256), 0, stream,
                       nf, pos, valid, adj, ew1, ew2, cw1, cw2, nw1, nw2, iw,
                       T0, T1, out);
}

// Round 2
// 270.514 us; speedup vs baseline: 3.2083x; 3.2083x over previous
//
#include <hip/hip_runtime.h>
#include <hip/hip_bf16.h>

// EGCL, MFMA version. B=8, N=256, NF=H=128.
// edge_input@ew1 factorized: T0[i] + T1[j] + dist*ew1[256] + adj*ew1[257].
// GEMM1/GEMM2 per 128-j tile via mfma_f32_16x16x32_bf16, swapped operands:
//   mT[h][j]  = sum_k ew2T[h][k] * h1[j][k]
//   c1T[h][j] = sum_k cw1T[h][k] * m[j][k]
// All LDS tiles XOR-swizzled: elem_idx ^= (row&7)<<3  (byte ^= (row&7)<<4).

#define BB 8
#define NN 256
#define HD 128
#define JT 128
#define NT (NN/JT)

typedef short bf16x8 __attribute__((ext_vector_type(8)));
typedef float f32x4  __attribute__((ext_vector_type(4)));

__device__ __forceinline__ float sigmoidf_(float x){ return 1.0f/(1.0f+__expf(-x)); }
__device__ __forceinline__ float siluf_(float x){ return x/(1.0f+__expf(-x)); }
__device__ __forceinline__ unsigned short f2bf(float x){
    unsigned int u = __float_as_uint(x);
    u += 0x7FFF + ((u>>16)&1);
    return (unsigned short)(u>>16);
}
__device__ __forceinline__ float bf2f(unsigned short h){
    return __uint_as_float(((unsigned int)h)<<16);
}

// ---------- prep kernels ----------

// T0/T1 (bf16): T0[bi][h] = sum_f nf[bi][f]*ew1[f][h]; T1 uses ew1[128+f][h]
__global__ __launch_bounds__(128) void precompute_T(
    const float* __restrict__ nf, const float* __restrict__ ew1,
    unsigned short* __restrict__ T0, unsigned short* __restrict__ T1)
{
    __shared__ float nfs[HD];
    const int bi = blockIdx.x;
    const int h  = threadIdx.x;
    nfs[h] = nf[(size_t)bi*HD + h];
    __syncthreads();
    float a0 = 0.f, a1 = 0.f;
    #pragma unroll 4
    for (int f = 0; f < HD; ++f){
        const float v = nfs[f];
        a0 = fmaf(v, ew1[f*HD + h],      a0);
        a1 = fmaf(v, ew1[(HD+f)*HD + h], a1);
    }
    T0[bi*HD + h] = f2bf(a0);
    T1[bi*HD + h] = f2bf(a1);
}

// transposed + bf16 + swizzled weights: dst[m][ (n*128+k) ^ ((n&7)<<3) ] = src_m[k][n]
__global__ __launch_bounds__(256) void prep_w(
    const float* __restrict__ ew2, const float* __restrict__ cw1,
    unsigned short* __restrict__ dst)
{
    const int e = blockIdx.x*256 + threadIdx.x;   // 0..32767
    const int m = e >> 14;
    const int rem = e & 16383;
    const int n = rem >> 7, k = rem & 127;
    const float* src = m ? cw1 : ew2;
    dst[m*16384 + (((n<<7) | k) ^ ((n&7)<<3))] = f2bf(src[k*HD + n]);
}

// ---------- main kernel ----------

#define GEMM128(SW, SX, ACC)                                                   \
    _Pragma("unroll")                                                          \
    for (int kk = 0; kk < 4; ++kk){                                            \
        const int kb = kk*32 + lg*8;                                           \
        bf16x8 afr[4], bfr[4];                                                 \
        _Pragma("unroll")                                                      \
        for (int mt = 0; mt < 4; ++mt){                                        \
            const int hr = wm*64 + mt*16 + lr;                                 \
            afr[mt] = *(const bf16x8*)&SW[((hr<<7) + kb) ^ ((hr&7)<<3)];       \
        }                                                                      \
        _Pragma("unroll")                                                      \
        for (int nt = 0; nt < 4; ++nt){                                        \
            const int jr = wn*64 + nt*16 + lr;                                 \
            bfr[nt] = *(const bf16x8*)&SX[((jr<<7) + kb) ^ ((jr&7)<<3)];       \
        }                                                                      \
        _Pragma("unroll")                                                      \
        for (int mt = 0; mt < 4; ++mt)                                         \
            _Pragma("unroll")                                                  \
            for (int nt = 0; nt < 4; ++nt)                                     \
                ACC[mt][nt] = __builtin_amdgcn_mfma_f32_16x16x32_bf16(         \
                    afr[mt], bfr[nt], ACC[mt][nt], 0, 0, 0);                   \
    }

__global__ __launch_bounds__(256) void egcl_main(
    const float* __restrict__ nf,  const float* __restrict__ pos,
    const float* __restrict__ valid, const float* __restrict__ adj,
    const float* __restrict__ ew1,
    const float* __restrict__ cw2,
    const float* __restrict__ nw1, const float* __restrict__ nw2,
    const float* __restrict__ iw,
    const unsigned short* __restrict__ T0u, const unsigned short* __restrict__ T1u,
    const unsigned short* __restrict__ wE,  const unsigned short* __restrict__ wC,
    float* __restrict__ out)
{
    __shared__ unsigned short sEw2T[16384];   // 32 KB, [h][k] swizzled
    __shared__ unsigned short sCw1T[16384];   // 32 KB, [h'][k] swizzled
    __shared__ unsigned short sH1[16384];     // 32 KB, [j][k] swizzled
    __shared__ unsigned short sM[16384];      // 32 KB, [j][h] swizzled
    __shared__ float gpart[2][JT];
    __shared__ float cpart[2][JT];
    __shared__ float gate_s[JT];
    __shared__ float coord_s[JT];
    __shared__ float msgp[2][HD];
    __shared__ float iwl[HD], cw2l[HD];
    __shared__ float ni[2*HD], n1l[HD], np2[2][HD];
    __shared__ float red3[2][3];

    const int tid = threadIdx.x;
    const int bi  = blockIdx.x;
    const int b   = bi >> 8;
    const int w   = tid >> 6;          // wave 0..3
    const int wm  = w & 1;             // h-half
    const int wn  = w >> 1;            // j-half
    const int l   = tid & 63, lr = l & 15, lg = l >> 4;
    const int hp  = tid & 63,  jq = tid >> 6;   // h1-compute mapping
    const int hh  = tid & 127, half = tid >> 7; // msg / node mapping

    // ---- stage weights into LDS (linear copy; data pre-swizzled) ----
    {
        const uint4* g0 = (const uint4*)wE;
        const uint4* g1 = (const uint4*)wC;
        uint4* s0 = (uint4*)sEw2T;
        uint4* s1 = (uint4*)sCw1T;
        #pragma unroll
        for (int r = 0; r < 8; ++r){
            s0[r*256 + tid] = g0[r*256 + tid];
            s1[r*256 + tid] = g1[r*256 + tid];
        }
    }
    if (tid < HD){ iwl[tid] = iw[tid]; cw2l[tid] = cw2[tid]; }

    // ---- per-thread constants ----
    const float t0a = bf2f(T0u[bi*HD + 2*hp]);
    const float t0b = bf2f(T0u[bi*HD + 2*hp + 1]);
    const float w6a = ew1[256*HD + 2*hp], w6b = ew1[256*HD + 2*hp + 1];
    const float w7a = ew1[257*HD + 2*hp], w7b = ew1[257*HD + 2*hp + 1];
    const float pix = pos[bi*3+0], piy = pos[bi*3+1], piz = pos[bi*3+2];
    const float validi = valid[bi];
    const unsigned short* __restrict__ T1b = T1u + (size_t)(b*NN)*HD;
    const float* __restrict__ posb   = pos + (size_t)(b*NN)*3;
    const float* __restrict__ adjrow = adj + (size_t)bi*NN;

    float msgacc0 = 0.f, msgacc1 = 0.f;
    float pax = 0.f, pay = 0.f, paz = 0.f;

    for (int t = 0; t < NT; ++t){
        const int j0 = t*JT;

        // ---- P1: h1 = silu(first-layer preact), bf16 into sH1 ----
        #pragma unroll 4
        for (int r = 0; r < 32; ++r){
            const int jl = jq*32 + r;
            const int j  = j0 + jl;
            const ushort2 t1v = *(const ushort2*)&T1b[(size_t)j*HD + 2*hp];
            const float pjx = posb[j*3+0], pjy = posb[j*3+1], pjz = posb[j*3+2];
            const float dx = pix-pjx, dy = piy-pjy, dz = piz-pjz;
            const float d2 = dx*dx + dy*dy + dz*dz;
            const float aj = adjrow[j];
            const float s0 = siluf_(t0a + bf2f(t1v.x) + d2*w6a + aj*w7a);
            const float s1 = siluf_(t0b + bf2f(t1v.y) + d2*w6b + aj*w7b);
            const unsigned int pk = ((unsigned int)f2bf(s1) << 16) | f2bf(s0);
            ((unsigned int*)sH1)[(jl*64 + hp) ^ ((jl&7)<<2)] = pk;
        }
        __syncthreads();   // A: h1 + weights ready

        // ---- P2: GEMM1  mT[h][j] ----
        {
            f32x4 acc[4][4];
            #pragma unroll
            for (int mt = 0; mt < 4; ++mt)
                #pragma unroll
                for (int nt = 0; nt < 4; ++nt)
                    acc[mt][nt] = (f32x4){0.f,0.f,0.f,0.f};

            GEMM128(sEw2T, sH1, acc)

            // silu -> m
            #pragma unroll
            for (int mt = 0; mt < 4; ++mt)
                #pragma unroll
                for (int nt = 0; nt < 4; ++nt)
                    #pragma unroll
                    for (int i = 0; i < 4; ++i)
                        acc[mt][nt][i] = siluf_(acc[mt][nt][i]);

            // gate partials: pg[nt] = sum over this wave's h of m[h][j]*iw[h]
            float pg[4] = {0.f,0.f,0.f,0.f};
            #pragma unroll
            for (int mt = 0; mt < 4; ++mt){
                const f32x4 iwv = *(const f32x4*)&iwl[wm*64 + mt*16 + lg*4];
                #pragma unroll
                for (int nt = 0; nt < 4; ++nt)
                    pg[nt] += acc[mt][nt][0]*iwv[0] + acc[mt][nt][1]*iwv[1]
                            + acc[mt][nt][2]*iwv[2] + acc[mt][nt][3]*iwv[3];
            }
            #pragma unroll
            for (int nt = 0; nt < 4; ++nt){
                pg[nt] += __shfl_xor(pg[nt], 16);
                pg[nt] += __shfl_xor(pg[nt], 32);
            }
            if (lg == 0){
                #pragma unroll
                for (int nt = 0; nt < 4; ++nt)
                    gpart[wm][wn*64 + nt*16 + lr] = pg[nt];
            }

            // m -> bf16 -> sM[j][h] (swizzled); 4 consecutive h per (mt,nt)
            #pragma unroll
            for (int mt = 0; mt < 4; ++mt){
                const int h0 = wm*64 + mt*16 + lg*4;
                #pragma unroll
                for (int nt = 0; nt < 4; ++nt){
                    const int jr = wn*64 + nt*16 + lr;
                    ushort4 mv;
                    mv.x = f2bf(acc[mt][nt][0]); mv.y = f2bf(acc[mt][nt][1]);
                    mv.z = f2bf(acc[mt][nt][2]); mv.w = f2bf(acc[mt][nt][3]);
                    *(ushort4*)&sM[((jr<<7) + h0) ^ ((jr&7)<<3)] = mv;
                }
            }
        }
        __syncthreads();   // B: m ready

        // ---- P3: GEMM2  c1T[h'][j], coord partials; gate combine ----
        {
            f32x4 acc[4][4];
            #pragma unroll
            for (int mt = 0; mt < 4; ++mt)
                #pragma unroll
                for (int nt = 0; nt < 4; ++nt)
                    acc[mt][nt] = (f32x4){0.f,0.f,0.f,0.f};

            GEMM128(sCw1T, sM, acc)

            float pc[4] = {0.f,0.f,0.f,0.f};
            #pragma unroll
            for (int mt = 0; mt < 4; ++mt){
                const f32x4 cwv = *(const f32x4*)&cw2l[wm*64 + mt*16 + lg*4];
                #pragma unroll
                for (int nt = 0; nt < 4; ++nt)
                    pc[nt] += siluf_(acc[mt][nt][0])*cwv[0] + siluf_(acc[mt][nt][1])*cwv[1]
                            + siluf_(acc[mt][nt][2])*cwv[2] + siluf_(acc[mt][nt][3])*cwv[3];
            }
            #pragma unroll
            for (int nt = 0; nt < 4; ++nt){
                pc[nt] += __shfl_xor(pc[nt], 16);
                pc[nt] += __shfl_xor(pc[nt], 32);
            }
            if (lg == 0){
                #pragma unroll
                for (int nt = 0; nt < 4; ++nt)
                    cpart[wm][wn*64 + nt*16 + lr] = pc[nt];
            }
            if (tid < JT) gate_s[tid] = sigmoidf_(gpart[0][tid] + gpart[1][tid]);
        }
        __syncthreads();   // C: cpart + gate_s ready

        // ---- P4: coord combine ----
        if (tid < JT) coord_s[tid] = cpart[0][tid] + cpart[1][tid];
        __syncthreads();   // D: coord_s ready

        // ---- P5: msg accumulation + pos accumulation ----
        #pragma unroll 8
        for (int jj2 = 0; jj2 < 64; jj2 += 2){
            const int jl0 = half*64 + jj2;
            const int jl1 = jl0 + 1;
            msgacc0 += gate_s[jl0] * bf2f(sM[((jl0<<7) + hh) ^ ((jl0&7)<<3)]);
            msgacc1 += gate_s[jl1] * bf2f(sM[((jl1<<7) + hh) ^ ((jl1&7)<<3)]);
        }
        if (tid < JT){
            const int j = j0 + tid;
            const float pjx = posb[j*3+0], pjy = posb[j*3+1], pjz = posb[j*3+2];
            const float dx = pix-pjx, dy = piy-pjy, dz = piz-pjz;
            const float d2 = dx*dx + dy*dy + dz*dz;
            const float inv = 1.0f / fmaxf(sqrtf(d2), 1e-10f);
            const float cd = coord_s[tid] * inv;
            pax = fmaf(dx, cd, pax);
            pay = fmaf(dy, cd, pay);
            paz = fmaf(dz, cd, paz);
        }
        // no barrier needed at loop seam (next writes are fenced by A/B)
    }

    // ---- finalize msg + pos ----
    msgp[half][hh] = msgacc0 + msgacc1;
    if (tid < JT){
        float sx = pax, sy = pay, sz = paz;
        #pragma unroll
        for (int off = 32; off >= 1; off >>= 1){
            sx += __shfl_down(sx, off);
            sy += __shfl_down(sy, off);
            sz += __shfl_down(sz, off);
        }
        if (l == 0){ red3[w][0] = sx; red3[w][1] = sy; red3[w][2] = sz; }
    }
    __syncthreads();

    const float scale = validi * (1.0f/NN);
    if (tid < HD){
        const float mg = (msgp[0][tid] + msgp[1][tid]) * scale;
        ni[tid]      = nf[(size_t)bi*HD + tid];
        ni[HD + tid] = mg;
    }
    if (tid == 0){
        out[(size_t)bi*3+0] = pix + (red3[0][0]+red3[1][0])*scale;
        out[(size_t)bi*3+1] = piy + (red3[0][1]+red3[1][1])*scale;
        out[(size_t)bi*3+2] = piz + (red3[0][2]+red3[1][2])*scale;
    }
    __syncthreads();

    // ---- node MLP (fp32, K split across halves) ----
    float p1 = 0.f;
    for (int f = 0; f < HD; ++f){
        const int ff = half*HD + f;
        p1 = fmaf(ni[ff], nw1[ff*HD + hh], p1);
    }
    np2[half][hh] = p1;
    __syncthreads();
    if (tid < HD) n1l[tid] = siluf_(np2[0][tid] + np2[1][tid]);
    __syncthreads();
    float p2 = 0.f;
    for (int k = 0; k < 64; ++k){
        const int kk2 = half*64 + k;
        p2 = fmaf(n1l[kk2], nw2[kk2*HD + hh], p2);
    }
    np2[half][hh] = p2;
    __syncthreads();
    if (tid < HD){
        out[(size_t)BB*NN*3 + (size_t)bi*HD + tid] =
            nf[(size_t)bi*HD + tid] + np2[0][tid] + np2[1][tid];
    }
}

extern "C" void kernel_launch(void* const* d_in, const int* in_sizes, int n_in,
                              void* d_out, int out_size, void* d_ws, size_t ws_size,
                              hipStream_t stream)
{
    const float* nf    = (const float*)d_in[0];
    const float* pos   = (const float*)d_in[1];
    const float* valid = (const float*)d_in[2];
    const float* adj   = (const float*)d_in[3];
    const float* ew1   = (const float*)d_in[4];
    const float* ew2   = (const float*)d_in[5];
    const float* cw1   = (const float*)d_in[6];
    const float* cw2   = (const float*)d_in[7];
    const float* nw1   = (const float*)d_in[8];
    const float* nw2   = (const float*)d_in[9];
    const float* iw    = (const float*)d_in[10];
    float* out = (float*)d_out;

    // ws layout: wE(32KB) | wC(32KB) | T0(512KB) | T1(512KB)  -> ~1.07MB
    unsigned short* wE  = (unsigned short*)d_ws;
    unsigned short* wC  = wE + 16384;
    unsigned short* T0u = wC + 16384;
    unsigned short* T1u = T0u + (size_t)BB*NN*HD;

    hipLaunchKernelGGL(prep_w, dim3(128), dim3(256), 0, stream, ew2, cw1, wE);
    hipLaunchKernelGGL(precompute_T, dim3(BB*NN), dim3(HD), 0, stream,
                       nf, ew1, T0u, T1u);
    hipLaunchKernelGGL(egcl_main, dim3(BB*NN), dim3(256), 0, stream,
                       nf, pos, valid, adj, ew1, cw2, nw1, nw2, iw,
                       T0u, T1u, wE, wC, out);
}

// Round 3
// 231.803 us; speedup vs baseline: 3.7441x; 1.1670x over previous
//
#include <hip/hip_runtime.h>
#include <hip/hip_bf16.h>

// EGCL, MFMA + register-resident weights. B=8, N=256, NF=H=128.
// edge_input@ew1 factorized: T0[i] + T1[j] + dist*ew1[256] + adj*ew1[257].
// Per block (one (b,i)), 4 waves (wm 2 x wn 2), j-tiles of 64, 4 iters.
// GEMM1: mT[h][j] = sum_k ew2T[h][k]*h1[j][k]; GEMM2: c1T = cw1T * mT.
// A-fragments (weights) live in VGPRs; B-fragments via swizzled LDS.

#define BB 8
#define NN 256
#define HD 128
#define JT 64
#define NT (NN/JT)

typedef short bf16x8 __attribute__((ext_vector_type(8)));
typedef float f32x4  __attribute__((ext_vector_type(4)));

__device__ __forceinline__ float sigmoidf_(float x){ return 1.0f/(1.0f+__expf(-x)); }
__device__ __forceinline__ float siluf_(float x){ return x/(1.0f+__expf(-x)); }
__device__ __forceinline__ unsigned int cvtpk_bf16(float lo, float hi){
    unsigned int r;
    asm("v_cvt_pk_bf16_f32 %0, %1, %2" : "=v"(r) : "v"(lo), "v"(hi));
    return r;
}
__device__ __forceinline__ unsigned short f2bf(float x){
    unsigned int u = __float_as_uint(x);
    u += 0x7FFF + ((u>>16)&1);
    return (unsigned short)(u>>16);
}
__device__ __forceinline__ float bf2f(unsigned short h){
    return __uint_as_float(((unsigned int)h)<<16);
}

#define MFMA_BF16(d,a,b) d = __builtin_amdgcn_mfma_f32_16x16x32_bf16(a, b, d, 0, 0, 0)

// ---------- prep kernels ----------

__global__ __launch_bounds__(128) void precompute_T(
    const float* __restrict__ nf, const float* __restrict__ ew1,
    unsigned short* __restrict__ T0, unsigned short* __restrict__ T1)
{
    __shared__ float nfs[HD];
    const int bi = blockIdx.x;
    const int h  = threadIdx.x;
    nfs[h] = nf[(size_t)bi*HD + h];
    __syncthreads();
    float a0 = 0.f, a1 = 0.f;
    #pragma unroll 4
    for (int f = 0; f < HD; ++f){
        const float v = nfs[f];
        a0 = fmaf(v, ew1[f*HD + h],      a0);
        a1 = fmaf(v, ew1[(HD+f)*HD + h], a1);
    }
    T0[bi*HD + h] = f2bf(a0);
    T1[bi*HD + h] = f2bf(a1);
}

// plain transposed bf16 weights: dst[m][h*128+k] = src_m[k][h]
__global__ __launch_bounds__(256) void prep_w(
    const float* __restrict__ ew2, const float* __restrict__ cw1,
    unsigned short* __restrict__ dst)
{
    const int e = blockIdx.x*256 + threadIdx.x;   // 0..32767
    const int m = e >> 14;
    const int rem = e & 16383;
    const int h = rem >> 7, k = rem & 127;
    const float* src = m ? cw1 : ew2;
    dst[e] = f2bf(src[k*HD + h]);
}

// ---------- main kernel ----------

__global__ __launch_bounds__(256, 2) void egcl_main(
    const float* __restrict__ nf,  const float* __restrict__ pos,
    const float* __restrict__ valid, const float* __restrict__ adj,
    const float* __restrict__ ew1,
    const float* __restrict__ cw2,
    const float* __restrict__ nw1, const float* __restrict__ nw2,
    const float* __restrict__ iw,
    const unsigned short* __restrict__ T0u, const unsigned short* __restrict__ T1u,
    const unsigned short* __restrict__ wE,  const unsigned short* __restrict__ wC,
    float* __restrict__ out)
{
    __shared__ unsigned short sH1[JT*HD];   // 16KB, [j][k] swizzled
    __shared__ unsigned short sM [JT*HD];   // 16KB, [j][h] swizzled
    __shared__ float gpart[2][JT];
    __shared__ float cpart[2][JT];
    __shared__ float gate_s[JT];
    __shared__ float msgp[2][HD];
    __shared__ float ni[2*HD], n1l[HD], np2[2][HD];
    __shared__ float red3[3];

    const int tid = threadIdx.x;
    const int bi  = blockIdx.x;
    const int b   = bi >> 8;
    const int w   = tid >> 6;
    const int wm  = w & 1;             // h-half (0: h 0-63, 1: h 64-127)
    const int wn  = w >> 1;            // j-half within 64-tile
    const int l   = tid & 63, lr = l & 15, lg = l >> 4;
    const int hp  = tid & 63,  jq = tid >> 6;   // P1 mapping
    const int hh  = tid & 127, half = tid >> 7; // node-MLP mapping

    // ---- load weight A-fragments into registers (row h = wm*64+mt*16+lr) ----
    bf16x8 aE[4][4], aC[4][4];
    {
        const unsigned short* pE = wE + (((wm*64 + lr) << 7) + lg*8);
        const unsigned short* pC = wC + (((wm*64 + lr) << 7) + lg*8);
        #pragma unroll
        for (int mt = 0; mt < 4; ++mt)
            #pragma unroll
            for (int kk = 0; kk < 4; ++kk){
                aE[mt][kk] = *(const bf16x8*)(pE + (mt*16 << 7) + kk*32);
                aC[mt][kk] = *(const bf16x8*)(pC + (mt*16 << 7) + kk*32);
            }
    }

    // ---- per-thread P1 constants ----
    const float t0a = bf2f(T0u[bi*HD + 2*hp]);
    const float t0b = bf2f(T0u[bi*HD + 2*hp + 1]);
    const float w6a = ew1[256*HD + 2*hp], w6b = ew1[256*HD + 2*hp + 1];
    const float w7a = ew1[257*HD + 2*hp], w7b = ew1[257*HD + 2*hp + 1];
    const float pix = pos[bi*3+0], piy = pos[bi*3+1], piz = pos[bi*3+2];
    const float validi = valid[bi];
    const unsigned short* __restrict__ T1b = T1u + (size_t)(b*NN)*HD;
    const float* __restrict__ posb   = pos + (size_t)(b*NN)*3;
    const float* __restrict__ adjrow = adj + (size_t)bi*NN;

    float msgacc[16];
    #pragma unroll
    for (int s = 0; s < 16; ++s) msgacc[s] = 0.f;
    float pax = 0.f, pay = 0.f, paz = 0.f;   // tid<64 only

    for (int t = 0; t < NT; ++t){
        const int j0 = t*JT;

        // ---- P1: h1 = silu(first-layer preact) -> sH1 (bf16, swizzled) ----
        #pragma unroll 2
        for (int r = 0; r < 16; ++r){
            const int jl = jq*16 + r;
            const int j  = j0 + jl;
            const ushort2 t1v = *(const ushort2*)&T1b[(size_t)j*HD + 2*hp];
            const float pjx = posb[j*3+0], pjy = posb[j*3+1], pjz = posb[j*3+2];
            const float dx = pix-pjx, dy = piy-pjy, dz = piz-pjz;
            const float d2 = dx*dx + dy*dy + dz*dz;
            const float aj = adjrow[j];
            const float s0 = siluf_(t0a + bf2f(t1v.x) + d2*w6a + aj*w7a);
            const float s1 = siluf_(t0b + bf2f(t1v.y) + d2*w6b + aj*w7b);
            ((unsigned int*)sH1)[(jl*64 + hp) ^ ((jl&7)<<2)] = cvtpk_bf16(s0, s1);
        }
        __syncthreads();   // A: h1 ready

        // ---- GEMM1: m = silu(ew2T @ h1T) ----
        f32x4 acc[4][2];
        #pragma unroll
        for (int mt = 0; mt < 4; ++mt){
            acc[mt][0] = (f32x4){0.f,0.f,0.f,0.f};
            acc[mt][1] = (f32x4){0.f,0.f,0.f,0.f};
        }
        {
            const int jb0 = wn*32 + lr;
            const int jb1 = jb0 + 16;
            #pragma unroll
            for (int kk = 0; kk < 4; ++kk){
                const int kb = kk*32 + lg*8;
                const bf16x8 b0 = *(const bf16x8*)&sH1[((jb0<<7) + kb) ^ ((jb0&7)<<3)];
                const bf16x8 b1 = *(const bf16x8*)&sH1[((jb1<<7) + kb) ^ ((jb1&7)<<3)];
                #pragma unroll
                for (int mt = 0; mt < 4; ++mt){
                    MFMA_BF16(acc[mt][0], aE[mt][kk], b0);
                    MFMA_BF16(acc[mt][1], aE[mt][kk], b1);
                }
            }
        }

        // ---- GEMM1 epilogue: silu, gate partials, m -> sM ----
        {
            float pg[2] = {0.f, 0.f};
            #pragma unroll
            for (int mt = 0; mt < 4; ++mt){
                const f32x4 iwv = *(const f32x4*)&iw[wm*64 + mt*16 + lg*4];
                #pragma unroll
                for (int nt = 0; nt < 2; ++nt){
                    #pragma unroll
                    for (int i = 0; i < 4; ++i){
                        acc[mt][nt][i] = siluf_(acc[mt][nt][i]);
                        pg[nt] = fmaf(acc[mt][nt][i], iwv[i], pg[nt]);
                    }
                    const int jr = wn*32 + nt*16 + lr;
                    uint2 mv;
                    mv.x = cvtpk_bf16(acc[mt][nt][0], acc[mt][nt][1]);
                    mv.y = cvtpk_bf16(acc[mt][nt][2], acc[mt][nt][3]);
                    *(uint2*)&sM[((jr<<7) + wm*64 + mt*16 + lg*4) ^ ((jr&7)<<3)] = mv;
                }
            }
            pg[0] += __shfl_xor(pg[0], 16); pg[0] += __shfl_xor(pg[0], 32);
            pg[1] += __shfl_xor(pg[1], 16); pg[1] += __shfl_xor(pg[1], 32);
            if (lg == 0){
                gpart[wm][wn*32 + lr]      = pg[0];
                gpart[wm][wn*32 + 16 + lr] = pg[1];
            }
        }
        __syncthreads();   // B: gpart + sM ready

        if (tid < JT) gate_s[tid] = sigmoidf_(gpart[0][tid] + gpart[1][tid]);
        __syncthreads();   // B2: gate ready

        // ---- msg accumulation from live m registers ----
        #pragma unroll
        for (int nt = 0; nt < 2; ++nt){
            const float g = gate_s[wn*32 + nt*16 + lr];
            #pragma unroll
            for (int mt = 0; mt < 4; ++mt)
                #pragma unroll
                for (int i = 0; i < 4; ++i)
                    msgacc[mt*4+i] = fmaf(acc[mt][nt][i], g, msgacc[mt*4+i]);
        }

        // ---- GEMM2: c1 = silu(cw1T @ mT), coord partials ----
        #pragma unroll
        for (int mt = 0; mt < 4; ++mt){
            acc[mt][0] = (f32x4){0.f,0.f,0.f,0.f};
            acc[mt][1] = (f32x4){0.f,0.f,0.f,0.f};
        }
        {
            const int jb0 = wn*32 + lr;
            const int jb1 = jb0 + 16;
            #pragma unroll
            for (int kk = 0; kk < 4; ++kk){
                const int kb = kk*32 + lg*8;
                const bf16x8 b0 = *(const bf16x8*)&sM[((jb0<<7) + kb) ^ ((jb0&7)<<3)];
                const bf16x8 b1 = *(const bf16x8*)&sM[((jb1<<7) + kb) ^ ((jb1&7)<<3)];
                #pragma unroll
                for (int mt = 0; mt < 4; ++mt){
                    MFMA_BF16(acc[mt][0], aC[mt][kk], b0);
                    MFMA_BF16(acc[mt][1], aC[mt][kk], b1);
                }
            }
        }
        {
            float pc[2] = {0.f, 0.f};
            #pragma unroll
            for (int mt = 0; mt < 4; ++mt){
                const f32x4 cwv = *(const f32x4*)&cw2[wm*64 + mt*16 + lg*4];
                #pragma unroll
                for (int nt = 0; nt < 2; ++nt)
                    #pragma unroll
                    for (int i = 0; i < 4; ++i)
                        pc[nt] = fmaf(siluf_(acc[mt][nt][i]), cwv[i], pc[nt]);
            }
            pc[0] += __shfl_xor(pc[0], 16); pc[0] += __shfl_xor(pc[0], 32);
            pc[1] += __shfl_xor(pc[1], 16); pc[1] += __shfl_xor(pc[1], 32);
            if (lg == 0){
                cpart[wm][wn*32 + lr]      = pc[0];
                cpart[wm][wn*32 + 16 + lr] = pc[1];
            }
        }
        __syncthreads();   // C: cpart ready

        // ---- pos accumulation (threads 0..63, one j each) ----
        if (tid < JT){
            const float c = cpart[0][tid] + cpart[1][tid];
            const int j = j0 + tid;
            const float pjx = posb[j*3+0], pjy = posb[j*3+1], pjz = posb[j*3+2];
            const float dx = pix-pjx, dy = piy-pjy, dz = piz-pjz;
            const float d2 = dx*dx + dy*dy + dz*dz;
            const float inv = 1.0f / fmaxf(sqrtf(d2), 1e-10f);
            const float cd = c * inv;
            pax = fmaf(dx, cd, pax);
            pay = fmaf(dy, cd, pay);
            paz = fmaf(dz, cd, paz);
        }
        // next P1 write is fenced by barriers B/B2/C relative to all reads
    }

    // ---- finalize msg: reduce over lr lanes, combine wn halves via LDS ----
    #pragma unroll
    for (int s = 0; s < 16; ++s){
        msgacc[s] += __shfl_xor(msgacc[s], 1);
        msgacc[s] += __shfl_xor(msgacc[s], 2);
        msgacc[s] += __shfl_xor(msgacc[s], 4);
        msgacc[s] += __shfl_xor(msgacc[s], 8);
    }
    if (lr == 0){
        #pragma unroll
        for (int mt = 0; mt < 4; ++mt)
            #pragma unroll
            for (int i = 0; i < 4; ++i)
                msgp[wn][wm*64 + mt*16 + lg*4 + i] = msgacc[mt*4+i];
    }

    // ---- finalize pos: wave-0 reduce ----
    if (w == 0){
        float sx = pax, sy = pay, sz = paz;
        #pragma unroll
        for (int off = 1; off <= 32; off <<= 1){
            sx += __shfl_xor(sx, off);
            sy += __shfl_xor(sy, off);
            sz += __shfl_xor(sz, off);
        }
        if (l == 0){ red3[0] = sx; red3[1] = sy; red3[2] = sz; }
    }
    __syncthreads();

    const float scale = validi * (1.0f/NN);
    if (tid < HD){
        ni[tid]      = nf[(size_t)bi*HD + tid];
        ni[HD + tid] = (msgp[0][tid] + msgp[1][tid]) * scale;
    }
    if (tid == 0){
        out[(size_t)bi*3+0] = pix + red3[0]*scale;
        out[(size_t)bi*3+1] = piy + red3[1]*scale;
        out[(size_t)bi*3+2] = piz + red3[2]*scale;
    }
    __syncthreads();

    // ---- node MLP (fp32, K split across halves) ----
    float p1 = 0.f;
    for (int f = 0; f < HD; ++f){
        const int ff = half*HD + f;
        p1 = fmaf(ni[ff], nw1[ff*HD + hh], p1);
    }
    np2[half][hh] = p1;
    __syncthreads();
    if (tid < HD) n1l[tid] = siluf_(np2[0][tid] + np2[1][tid]);
    __syncthreads();
    float p2 = 0.f;
    for (int k = 0; k < 64; ++k){
        const int kk2 = half*64 + k;
        p2 = fmaf(n1l[kk2], nw2[kk2*HD + hh], p2);
    }
    np2[half][hh] = p2;
    __syncthreads();
    if (tid < HD){
        out[(size_t)BB*NN*3 + (size_t)bi*HD + tid] =
            nf[(size_t)bi*HD + tid] + np2[0][tid] + np2[1][tid];
    }
}

extern "C" void kernel_launch(void* const* d_in, const int* in_sizes, int n_in,
                              void* d_out, int out_size, void* d_ws, size_t ws_size,
                              hipStream_t stream)
{
    const float* nf    = (const float*)d_in[0];
    const float* pos   = (const float*)d_in[1];
    const float* valid = (const float*)d_in[2];
    const float* adj   = (const float*)d_in[3];
    const float* ew1   = (const float*)d_in[4];
    const float* ew2   = (const float*)d_in[5];
    const float* cw1   = (const float*)d_in[6];
    const float* cw2   = (const float*)d_in[7];
    const float* nw1   = (const float*)d_in[8];
    const float* nw2   = (const float*)d_in[9];
    const float* iw    = (const float*)d_in[10];
    float* out = (float*)d_out;

    // ws layout: wE(32KB) | wC(32KB) | T0(512KB) | T1(512KB)
    unsigned short* wE  = (unsigned short*)d_ws;
    unsigned short* wC  = wE + 16384;
    unsigned short* T0u = wC + 16384;
    unsigned short* T1u = T0u + (size_t)BB*NN*HD;

    hipLaunchKernelGGL(prep_w, dim3(128), dim3(256), 0, stream, ew2, cw1, wE);
    hipLaunchKernelGGL(precompute_T, dim3(BB*NN), dim3(HD), 0, stream,
                       nf, ew1, T0u, T1u);
    hipLaunchKernelGGL(egcl_main, dim3(BB*NN), dim3(256), 0, stream,
                       nf, pos, valid, adj, ew1, cw2, nw1, nw2, iw,
                       T0u, T1u, wE, wC, out);
}